// Round 12
// baseline (204.573 us; speedup 1.0000x reference)
//
#include <hip/hip_runtime.h>
#include <hip/hip_bf16.h>

typedef __bf16 bf16x8 __attribute__((ext_vector_type(8)));
typedef __bf16 bf16x4 __attribute__((ext_vector_type(4)));
typedef float f32x4 __attribute__((ext_vector_type(4)));
typedef unsigned short u16x8 __attribute__((ext_vector_type(8)));

// B=128, T=256, D=512, H=8, HD=64. M = B*T = 32768.

__device__ __forceinline__ unsigned short f2bf(float f) {
  unsigned u = __float_as_uint(f);
  u += 0x7fffu + ((u >> 16) & 1u);   // RNE
  return (unsigned short)(u >> 16);
}

__device__ __forceinline__ bf16x4 cvt4(f32x4 v) {
  bf16x4 o;
  o[0] = (__bf16)v[0]; o[1] = (__bf16)v[1]; o[2] = (__bf16)v[2]; o[3] = (__bf16)v[3];
  return o;
}

// async global->LDS, 16B per lane. LDS dest wave-uniform; HW adds lane*16.
__device__ __forceinline__ void async16(const void* g, void* l) {
  __builtin_amdgcn_global_load_lds(
      (const __attribute__((address_space(1))) void*)g,
      (__attribute__((address_space(3))) void*)l, 16, 0, 0);
}

// ---------------- x fp32 -> bf16 ----------------
__global__ __launch_bounds__(256) void k_convert_x(const float* __restrict__ in,
                                                   unsigned short* __restrict__ out) {
  int i = blockIdx.x * 256 + threadIdx.x;
  const float4* p = (const float4*)in + (size_t)i * 2;
  float4 a = p[0], b = p[1];
  u16x8 o;
  o[0] = f2bf(a.x); o[1] = f2bf(a.y); o[2] = f2bf(a.z); o[3] = f2bf(a.w);
  o[4] = f2bf(b.x); o[5] = f2bf(b.y); o[6] = f2bf(b.z); o[7] = f2bf(b.w);
  *((u16x8*)out + i) = o;
}

// ---------------- Wq/Wk/Wv fp32 [512][64] -> bf16 [64][512], 3 weights in one launch ----------------
__global__ __launch_bounds__(256) void k_transpose_w3(const float* __restrict__ w0,
                                                      const float* __restrict__ w1,
                                                      const float* __restrict__ w2,
                                                      unsigned short* __restrict__ out) {
  __shared__ unsigned short tile[64][72];
  int z = blockIdx.z;
  int wsel = z >> 3, hsel = z & 7;
  const float* inb = (wsel == 0 ? w0 : (wsel == 1 ? w1 : w2)) + (size_t)hsel * 512 * 64;
  unsigned short* outb = out + (size_t)z * 512 * 64;
  int r0 = blockIdx.y * 64;
  int tid = threadIdx.x;
  int r = tid >> 2, cq = (tid & 3) * 16;
  const float* src = inb + (size_t)(r0 + r) * 64 + cq;
#pragma unroll
  for (int i = 0; i < 16; i += 4) {
    float4 v = *(const float4*)(src + i);
    tile[r][cq + i + 0] = f2bf(v.x);
    tile[r][cq + i + 1] = f2bf(v.y);
    tile[r][cq + i + 2] = f2bf(v.z);
    tile[r][cq + i + 3] = f2bf(v.w);
  }
  __syncthreads();
  int cr = tid >> 2, rq = (tid & 3) * 16;
  u16x8 o0, o1;
#pragma unroll
  for (int i = 0; i < 8; ++i) o0[i] = tile[rq + i][cr];
#pragma unroll
  for (int i = 0; i < 8; ++i) o1[i] = tile[rq + 8 + i][cr];
  unsigned short* dst = outb + (size_t)cr * 512 + r0 + rq;
  *(u16x8*)dst = o0;
  *(u16x8*)(dst + 8) = o1;
}

// ---------------- Wo fp32 [512][512] -> bf16 [512][512]^T ----------------
__global__ __launch_bounds__(256) void k_transpose_w(const float* __restrict__ in,
                                                     unsigned short* __restrict__ out,
                                                     int rows, int cols) {
  __shared__ unsigned short tile[64][72];
  int c0 = blockIdx.x * 64, r0 = blockIdx.y * 64;
  int tid = threadIdx.x;
  int r = tid >> 2, cq = (tid & 3) * 16;
  const float* src = in + (size_t)(r0 + r) * cols + c0 + cq;
#pragma unroll
  for (int i = 0; i < 16; i += 4) {
    float4 v = *(const float4*)(src + i);
    tile[r][cq + i + 0] = f2bf(v.x);
    tile[r][cq + i + 1] = f2bf(v.y);
    tile[r][cq + i + 2] = f2bf(v.z);
    tile[r][cq + i + 3] = f2bf(v.w);
  }
  __syncthreads();
  int cr = tid >> 2, rq = (tid & 3) * 16;
  u16x8 o0, o1;
#pragma unroll
  for (int i = 0; i < 8; ++i) o0[i] = tile[rq + i][cr];
#pragma unroll
  for (int i = 0; i < 8; ++i) o1[i] = tile[rq + 8 + i][cr];
  unsigned short* dst = out + (size_t)(c0 + cr) * rows + r0 + rq;
  *(u16x8*)dst = o0;
  *(u16x8*)(dst + 8) = o1;
}

// ---------------- 256x256x(K=512) GEMM, 4-phase, minimal sync (R9 structure) ----------------
// KIND 0: x*Wqk^T -> Q,K [B,H,T,HD]; Q pre-scaled by 0.125*log2e for exp2 softmax. grid 512.
// KIND 1: a*Wo^T + bo -> fp32 out. grid 256.
// KIND 2: x*Wv^T -> V^T [B,H,HD,T]. grid 256.
template <int KIND>
__global__ __launch_bounds__(512, 1) void k_gemmP(
    const unsigned short* __restrict__ A,
    const unsigned short* __restrict__ Bmat,
    unsigned short* __restrict__ O0,
    unsigned short* __restrict__ O1,
    const float* __restrict__ bo,
    float* __restrict__ outf) {
  __shared__ unsigned short smem[65536];   // 2 bufs x (A[256][64] | B[256][64])
  const int P = (KIND == 0) ? 64 : 32;     // blocks per XCD
  int xcd = blockIdx.x & 7, g = blockIdx.x >> 3;
  int w = xcd * P + g;
  int mt, nt;
  if (KIND == 0) { mt = w >> 2; nt = w & 3; }
  else           { mt = w >> 1; nt = w & 1; }
  int m0 = mt * 256, n0 = nt * 256;
  int tid = threadIdx.x;
  int wid = tid >> 6, lane = tid & 63;
  int lr = lane & 15, lg = lane >> 4;
  int wm = wid >> 2, wn = wid & 3;

  int srow_off = wid * 16 + (lane >> 3);
  int schunk = (lane & 7) ^ (lane >> 3);   // inverse-swizzled source chunk (rule 21)
  auto stageA = [&](int kb, int buf, int half) {
#pragma unroll
    for (int j = 0; j < 2; ++j) {
      int row = half * 128 + srow_off + j * 8;
      async16(A + (size_t)(m0 + row) * 512 + kb * 64 + schunk * 8,
              smem + buf * 32768 + half * 8192 + (wid * 2 + j) * 512);
    }
  };
  auto stageB = [&](int kb, int buf, int half) {
#pragma unroll
    for (int j = 0; j < 2; ++j) {
      int row = half * 128 + srow_off + j * 8;
      async16(Bmat + (size_t)(n0 + row) * 512 + kb * 64 + schunk * 8,
              smem + buf * 32768 + 16384 + half * 8192 + (wid * 2 + j) * 512);
    }
  };
  auto lda = [&](int buf, int mi, int k32) -> bf16x8 {
    int row = mi * 32 + wm * 16 + lr;
    int ch = (k32 * 4 + lg) ^ (lr & 7);
    return *(const bf16x8*)&smem[buf * 32768 + row * 64 + ch * 8];
  };
  auto ldb = [&](int buf, int ni, int k32) -> bf16x8 {
    int row = ni * 64 + wn * 16 + lr;
    int ch = (k32 * 4 + lg) ^ (lr & 7);
    return *(const bf16x8*)&smem[buf * 32768 + 16384 + row * 64 + ch * 8];
  };

  f32x4 acc[8][4];
#pragma unroll
  for (int mi = 0; mi < 8; ++mi)
#pragma unroll
    for (int ni = 0; ni < 4; ++ni) acc[mi][ni] = (f32x4){0.f, 0.f, 0.f, 0.f};

#define MF(dst, afrag, bfrag)                                                        \
  if constexpr (KIND == 2)                                                           \
    dst = __builtin_amdgcn_mfma_f32_16x16x32_bf16(afrag, bfrag, dst, 0, 0, 0);       \
  else                                                                               \
    dst = __builtin_amdgcn_mfma_f32_16x16x32_bf16(bfrag, afrag, dst, 0, 0, 0);

  // prologue: tile0 halves [A0,B0,A1,B1]; wait A0,B0 (leave A1,B1 in flight)
  stageA(0, 0, 0); stageB(0, 0, 0); stageA(0, 0, 1); stageB(0, 0, 1);
  asm volatile("s_waitcnt vmcnt(4)" ::: "memory");
  __builtin_amdgcn_s_barrier();
  asm volatile("" ::: "memory");

  bf16x8 a03[4][2], a47[4][2], b01[2][2], b23[2][2];
#pragma unroll
  for (int t = 0; t < 8; ++t) {
    int buf = t & 1, nbuf = buf ^ 1;
    const bool st = (t < 7);
    // ---- phase 1: read a03(A0)+b01(B0); stage A0(t+1); MFMA Q00 ----
#pragma unroll
    for (int mi = 0; mi < 4; ++mi) { a03[mi][0] = lda(buf, mi, 0); a03[mi][1] = lda(buf, mi, 1); }
#pragma unroll
    for (int ni = 0; ni < 2; ++ni) { b01[ni][0] = ldb(buf, ni, 0); b01[ni][1] = ldb(buf, ni, 1); }
    if (st) stageA(t + 1, nbuf, 0);
    asm volatile("" ::: "memory");
    __builtin_amdgcn_s_setprio(1);
#pragma unroll
    for (int mi = 0; mi < 4; ++mi)
#pragma unroll
      for (int ni = 0; ni < 2; ++ni)
#pragma unroll
        for (int k = 0; k < 2; ++k) { MF(acc[mi][ni], a03[mi][k], b01[ni][k]); }
    __builtin_amdgcn_s_setprio(0);
    if (st) asm volatile("s_waitcnt vmcnt(4)" ::: "memory");
    else    asm volatile("s_waitcnt vmcnt(2)" ::: "memory");
    __builtin_amdgcn_s_barrier();
    asm volatile("" ::: "memory");
    // ---- phase 2: read a47(A1); stage B0(t+1); MFMA Q10 ----
#pragma unroll
    for (int mi = 0; mi < 4; ++mi) { a47[mi][0] = lda(buf, mi + 4, 0); a47[mi][1] = lda(buf, mi + 4, 1); }
    if (st) stageB(t + 1, nbuf, 0);
    asm volatile("" ::: "memory");
    __builtin_amdgcn_s_setprio(1);
#pragma unroll
    for (int mi = 0; mi < 4; ++mi)
#pragma unroll
      for (int ni = 0; ni < 2; ++ni)
#pragma unroll
        for (int k = 0; k < 2; ++k) { MF(acc[mi + 4][ni], a47[mi][k], b01[ni][k]); }
    __builtin_amdgcn_s_setprio(0);
    if (st) asm volatile("s_waitcnt vmcnt(4)" ::: "memory");
    else    asm volatile("s_waitcnt vmcnt(0)" ::: "memory");
    __builtin_amdgcn_s_barrier();
    asm volatile("" ::: "memory");
    // ---- phase 3: read b23(B1); stage A1(t+1); MFMA Q11; NO vmcnt ----
#pragma unroll
    for (int ni = 0; ni < 2; ++ni) { b23[ni][0] = ldb(buf, ni + 2, 0); b23[ni][1] = ldb(buf, ni + 2, 1); }
    if (st) stageA(t + 1, nbuf, 1);
    asm volatile("" ::: "memory");
    __builtin_amdgcn_s_setprio(1);
#pragma unroll
    for (int mi = 0; mi < 4; ++mi)
#pragma unroll
      for (int ni = 0; ni < 2; ++ni)
#pragma unroll
        for (int k = 0; k < 2; ++k) { MF(acc[mi + 4][ni + 2], a47[mi][k], b23[ni][k]); }
    __builtin_amdgcn_s_setprio(0);
    __builtin_amdgcn_s_barrier();
    asm volatile("" ::: "memory");
    // ---- phase 4: stage B1(t+1); MFMA Q01; vmcnt(4) ----
    if (st) stageB(t + 1, nbuf, 1);
    asm volatile("" ::: "memory");
    __builtin_amdgcn_s_setprio(1);
#pragma unroll
    for (int mi = 0; mi < 4; ++mi)
#pragma unroll
      for (int ni = 0; ni < 2; ++ni)
#pragma unroll
        for (int k = 0; k < 2; ++k) { MF(acc[mi][ni + 2], a03[mi][k], b23[ni][k]); }
    __builtin_amdgcn_s_setprio(0);
    if (st) asm volatile("s_waitcnt vmcnt(4)" ::: "memory");
    __builtin_amdgcn_s_barrier();
    asm volatile("" ::: "memory");
  }
#undef MF

  // ---- epilogues ----
  if constexpr (KIND == 0) {
    int z = n0 >> 9;
    if (z == 0) {
      // fold softmax scale + log2(e) into Q: exp(S/8) == exp2(S * 0.125*log2e)
#pragma unroll
      for (int mi = 0; mi < 8; ++mi)
#pragma unroll
        for (int ni = 0; ni < 4; ++ni) acc[mi][ni] *= 0.18033688011112042f;
    }
    int hbase = (n0 & 511) >> 6;
    int hd0 = wn * 16 + lg * 4;
#pragma unroll
    for (int ni = 0; ni < 4; ++ni) {
      unsigned short* outp = (z ? O1 : O0) + (size_t)(mt * 8 + hbase + ni) * 16384;
#pragma unroll
      for (int mi = 0; mi < 8; ++mi) {
        int tq = mi * 32 + wm * 16 + lr;
        *(bf16x4*)&outp[(size_t)tq * 64 + hd0] = cvt4(acc[mi][ni]);
      }
    }
  } else if constexpr (KIND == 1) {
#pragma unroll
    for (int ni = 0; ni < 4; ++ni) {
      int nb = n0 + ni * 64 + wn * 16 + lg * 4;
      float4 b4 = *(const float4*)&bo[nb];
#pragma unroll
      for (int mi = 0; mi < 8; ++mi) {
        int mg = m0 + mi * 32 + wm * 16 + lr;
        float4 o;
        o.x = acc[mi][ni][0] + b4.x; o.y = acc[mi][ni][1] + b4.y;
        o.z = acc[mi][ni][2] + b4.z; o.w = acc[mi][ni][3] + b4.w;
        *(float4*)&outf[(size_t)mg * 512 + nb] = o;
      }
    }
  } else {
    int hbase = n0 >> 6;
    int hd = wn * 16 + lr;
#pragma unroll
    for (int ni = 0; ni < 4; ++ni) {
      unsigned short* outp = O0 + (size_t)(mt * 8 + hbase + ni) * 16384;
#pragma unroll
      for (int mi = 0; mi < 8; ++mi) {
        int tq = mi * 32 + wm * 16 + lg * 4;
        *(bf16x4*)&outp[(size_t)hd * 256 + tq] = cvt4(acc[mi][ni]);
      }
    }
  }
}

// ---------------- fused causal attention v5: immediate-offset LDS, barrier-free body ----------------
// K/V reg-staged (global->reg->ds_write) into k-slice-major padded layouts:
//   Ksh[2][256][34]  (slice = 32-short k-half; row stride 34 shorts, odd dword stride)
//   Vsh[8][64][34]   (slice = k32)
// Every loop ds_read = wave-fixed base (lr*34+lg*8) + COMPILE-TIME offset -> folds to
// ds_read offset:N immediates, deleting the ~1700 addr-VALU/wave that R10 showed
// (VALUBusy 41% with flat dur). One __syncthreads; body barrier-free -> balanced
// {wid,15-wid} chunk pairs (17 tiles/wave).
__global__ __launch_bounds__(512, 4) void k_attn2(
    const unsigned short* __restrict__ Qb,
    const unsigned short* __restrict__ Kb,
    const unsigned short* __restrict__ Vtb,
    unsigned short* __restrict__ Ob) {  // [B,T,512] bf16 (concat heads)
  __shared__ unsigned short Ksh[2 * 256 * 34];   // 34816 B
  __shared__ unsigned short Vsh[8 * 64 * 34];    // 34816 B
  __shared__ unsigned short Ps[8][16][36];       // 9216 B  (total 78848 -> 2 blocks/CU)
  int bh = blockIdx.x;
  int tid = threadIdx.x, wid = tid >> 6, lane = tid & 63, lr = lane & 15, lg = lane >> 4;
  int bb = bh >> 3, h = bh & 7;
  const unsigned short* Kg = Kb + (size_t)bh * 16384;
  const unsigned short* Vg = Vtb + (size_t)bh * 16384;
  // ---- reg-stage K and V (8x16B global loads -> 8 ds_write_b128) ----
  int4 gk[4], gv[4];
#pragma unroll
  for (int j = 0; j < 4; ++j) {
    int ck = tid * 4 + j;                       // 2048 16B-chunks of K
    gk[j] = *(const int4*)(Kg + (ck >> 3) * 64 + (ck & 7) * 8);
    int cv = tid * 4 + j;                       // 2048 16B-chunks of V
    gv[j] = *(const int4*)(Vg + (cv >> 5) * 256 + (cv & 31) * 8);
  }
  // Q prefetch for both chunks (overlaps the global loads above)
  int ci0 = wid, ci1 = 15 - wid;
  const unsigned short* q0 = Qb + (size_t)bh * 16384 + (size_t)(ci0 * 16 + lr) * 64 + lg * 8;
  const unsigned short* q1 = Qb + (size_t)bh * 16384 + (size_t)(ci1 * 16 + lr) * 64 + lg * 8;
  bf16x8 bq0a = *(const bf16x8*)q0;
  bf16x8 bq0b = *(const bf16x8*)(q0 + 32);
  bf16x8 bq1a = *(const bf16x8*)q1;
  bf16x8 bq1b = *(const bf16x8*)(q1 + 32);
#pragma unroll
  for (int j = 0; j < 4; ++j) {
    int ck = tid * 4 + j;
    int rr = ck >> 3, o = ck & 7;
    *(int4*)&Ksh[(o >> 2) * 8704 + rr * 34 + (o & 3) * 8] = gk[j];
    int cv = tid * 4 + j;
    int vr = cv >> 5, vo = cv & 31;
    *(int4*)&Vsh[(vo >> 2) * 2176 + vr * 34 + (vo & 3) * 8] = gv[j];
  }
  __syncthreads();

  const unsigned short* kbase = &Ksh[lr * 34 + lg * 8];   // + nt*544 + slice*8704
  const unsigned short* vbase = &Vsh[lr * 34 + lg * 8];   // + kk*2176 + vt*544
  unsigned short* psw = &Ps[wid][lr][0];                  // writes: +lg*4, +16+lg*4; read: +lg*8

  auto do_chunk = [&](int ci, bf16x8 bqa, bf16x8 bqb) {
    int t0 = ci * 16, trow = t0 + lr;
    int ntV = ci + 1;
    int nk32 = (ntV + 1) >> 1;
    f32x4 acc[16];
#pragma unroll
    for (int nt = 0; nt < 16; ++nt)
      if (nt < ntV) {
        acc[nt] = (f32x4){0.f, 0.f, 0.f, 0.f};
        bf16x8 ak0 = *(const bf16x8*)(kbase + nt * 544);
        acc[nt] = __builtin_amdgcn_mfma_f32_16x16x32_bf16(ak0, bqa, acc[nt], 0, 0, 0);
        bf16x8 ak1 = *(const bf16x8*)(kbase + nt * 544 + 8704);
        acc[nt] = __builtin_amdgcn_mfma_f32_16x16x32_bf16(ak1, bqb, acc[nt], 0, 0, 0);
      }
    // acc[nt][r] = S'[t=trow][s=nt*16+lg*4+r], pre-scaled for exp2
    float m0c = -3.0e38f, m1c = -3.0e38f;
#pragma unroll
    for (int nt = 0; nt < 16; ++nt)
      if (nt < ntV) {
        if (nt == ci) {           // diagonal tile: the only masked one
#pragma unroll
          for (int r = 0; r < 4; ++r) {
            float v = acc[nt][r];
            if (lg * 4 + r > lr) v = -1.0e30f;
            acc[nt][r] = v;
          }
        }
        m0c = fmaxf(m0c, fmaxf(acc[nt][0], acc[nt][1]));
        m1c = fmaxf(m1c, fmaxf(acc[nt][2], acc[nt][3]));
      }
    float m = fmaxf(m0c, m1c);
    m = fmaxf(m, __shfl_xor(m, 16));
    m = fmaxf(m, __shfl_xor(m, 32));
    float s4[4] = {0.f, 0.f, 0.f, 0.f};
    bf16x4 pk[16];
#pragma unroll
    for (int nt = 0; nt < 16; ++nt)
      if (nt < ntV) {
#pragma unroll
        for (int r = 0; r < 4; ++r) {
          float p = exp2f(acc[nt][r] - m);
          s4[r] += p;
          pk[nt][r] = (__bf16)p;
        }
      }
    if (ntV & 1) {                // pad tile contributes zeros
      pk[ntV][0] = (__bf16)0.f; pk[ntV][1] = (__bf16)0.f;
      pk[ntV][2] = (__bf16)0.f; pk[ntV][3] = (__bf16)0.f;
    }
    float s = (s4[0] + s4[1]) + (s4[2] + s4[3]);
    s += __shfl_xor(s, 16);
    s += __shfl_xor(s, 32);
    float inv = 1.0f / s;
    // streaming P slot (same-wave LDS FIFO: in-order write->read->rewrite)
    *(bf16x4*)(psw + lg * 4) = pk[0];
    *(bf16x4*)(psw + 16 + lg * 4) = pk[1];
    f32x4 aco[4];
#pragma unroll
    for (int vt = 0; vt < 4; ++vt) aco[vt] = (f32x4){0.f, 0.f, 0.f, 0.f};
#pragma unroll
    for (int kk = 0; kk < 8; ++kk)
      if (kk < nk32) {
        bf16x8 pb = *(const bf16x8*)(psw + lg * 8);
        if (kk + 1 < nk32) {
          *(bf16x4*)(psw + lg * 4) = pk[2 * kk + 2];
          *(bf16x4*)(psw + 16 + lg * 4) = pk[2 * kk + 3];
        }
#pragma unroll
        for (int vt = 0; vt < 4; ++vt) {
          bf16x8 av = *(const bf16x8*)(vbase + kk * 2176 + vt * 544);
          aco[vt] = __builtin_amdgcn_mfma_f32_16x16x32_bf16(av, pb, aco[vt], 0, 0, 0);
        }
      }
    // aco[vt][r] = O[t=trow][hd=vt*16+lg*4+r]
    unsigned short* obase = Ob + (size_t)(bb * 256 + trow) * 512 + h * 64 + lg * 4;
#pragma unroll
    for (int vt = 0; vt < 4; ++vt) {
      bf16x4 ov;
#pragma unroll
      for (int r = 0; r < 4; ++r) ov[r] = (__bf16)(aco[vt][r] * inv);
      *(bf16x4*)(obase + vt * 16) = ov;
    }
  };

  do_chunk(ci0, bq0a, bq0b);
  do_chunk(ci1, bq1a, bq1b);
}

extern "C" void kernel_launch(void* const* d_in, const int* in_sizes, int n_in,
                              void* d_out, int out_size, void* d_ws, size_t ws_size,
                              hipStream_t stream) {
  (void)in_sizes; (void)n_in; (void)out_size; (void)ws_size;
  const float* x = (const float*)d_in[0];
  const float* Wq = (const float*)d_in[1];
  const float* Wk = (const float*)d_in[2];
  const float* Wv = (const float*)d_in[3];
  const float* Wo = (const float*)d_in[4];
  const float* bo = (const float*)d_in[5];
  float* out = (float*)d_out;
  char* ws = (char*)d_ws;
  const size_t MB = 1024 * 1024;
  unsigned short* Qb = (unsigned short*)(ws);             // 32 MB
  unsigned short* Kb = (unsigned short*)(ws + 32 * MB);   // 32 MB
  unsigned short* Vtb = (unsigned short*)(ws + 64 * MB);  // 32 MB
  unsigned short* xb = (unsigned short*)(ws + 96 * MB);   // 32 MB (reused as attn out)
  unsigned short* Wqt = (unsigned short*)(ws + 128 * MB); // [512][512]; Wkt follows -> [1024][512]
  unsigned short* Wkt = Wqt + 262144;
  unsigned short* Wvt = Wkt + 262144;
  unsigned short* Wot = Wvt + 262144;

  hipLaunchKernelGGL(k_convert_x, dim3(8192), dim3(256), 0, stream, x, xb);
  hipLaunchKernelGGL(k_transpose_w3, dim3(1, 8, 24), dim3(256), 0, stream, Wq, Wk, Wv, Wqt);
  hipLaunchKernelGGL(k_transpose_w, dim3(8, 8, 1), dim3(256), 0, stream, Wo, Wot, 512, 512);
  // QK projection: B = [Wqt;Wkt] = [1024][512]
  hipLaunchKernelGGL((k_gemmP<0>), dim3(512), dim3(512), 0, stream,
                     xb, Wqt, Qb, Kb, (const float*)nullptr, (float*)nullptr);
  // V projection -> V^T
  hipLaunchKernelGGL((k_gemmP<2>), dim3(256), dim3(512), 0, stream,
                     xb, Wvt, Vtb, (unsigned short*)nullptr, (const float*)nullptr, (float*)nullptr);
  hipLaunchKernelGGL(k_attn2, dim3(1024), dim3(512), 0, stream, Qb, Kb, Vtb, xb);
  hipLaunchKernelGGL((k_gemmP<1>), dim3(256), dim3(512), 0, stream,
                     xb, Wot, (unsigned short*)nullptr, (unsigned short*)nullptr, bo, out);
}

// Round 13
// 157.890 us; speedup vs baseline: 1.2957x; 1.2957x over previous
//
#include <hip/hip_runtime.h>
#include <hip/hip_bf16.h>

typedef __bf16 bf16x8 __attribute__((ext_vector_type(8)));
typedef __bf16 bf16x4 __attribute__((ext_vector_type(4)));
typedef float f32x4 __attribute__((ext_vector_type(4)));
typedef unsigned short u16x8 __attribute__((ext_vector_type(8)));
typedef short s16x4 __attribute__((ext_vector_type(4)));

// B=128, T=256, D=512, H=8, HD=64. M = B*T = 32768.

__device__ __forceinline__ unsigned short f2bf(float f) {
  unsigned u = __float_as_uint(f);
  u += 0x7fffu + ((u >> 16) & 1u);   // RNE
  return (unsigned short)(u >> 16);
}

__device__ __forceinline__ bf16x4 cvt4(f32x4 v) {
  bf16x4 o;
  o[0] = (__bf16)v[0]; o[1] = (__bf16)v[1]; o[2] = (__bf16)v[2]; o[3] = (__bf16)v[3];
  return o;
}

// K=16 bf16 MFMA: lane holds 4 elems at k=lg*4+j — matches pk[] layout exactly.
__device__ __forceinline__ f32x4 mfma16(bf16x4 a, bf16x4 b, f32x4 c) {
#if __has_builtin(__builtin_amdgcn_mfma_f32_16x16x16_bf16)
  return __builtin_amdgcn_mfma_f32_16x16x16_bf16(a, b, c, 0, 0, 0);
#elif __has_builtin(__builtin_amdgcn_mfma_f32_16x16x16bf16_1k)
  return __builtin_amdgcn_mfma_f32_16x16x16bf16_1k(
      __builtin_bit_cast(s16x4, a), __builtin_bit_cast(s16x4, b), c, 0, 0, 0);
#else
  f32x4 d = c;
  asm("v_mfma_f32_16x16x16_bf16 %0, %1, %2, %0" : "+v"(d) : "v"(a), "v"(b));
  return d;
#endif
}

// async global->LDS, 16B per lane. LDS dest wave-uniform; HW adds lane*16.
__device__ __forceinline__ void async16(const void* g, void* l) {
  __builtin_amdgcn_global_load_lds(
      (const __attribute__((address_space(1))) void*)g,
      (__attribute__((address_space(3))) void*)l, 16, 0, 0);
}

// ---------------- x fp32 -> bf16 ----------------
__global__ __launch_bounds__(256) void k_convert_x(const float* __restrict__ in,
                                                   unsigned short* __restrict__ out) {
  int i = blockIdx.x * 256 + threadIdx.x;
  const float4* p = (const float4*)in + (size_t)i * 2;
  float4 a = p[0], b = p[1];
  u16x8 o;
  o[0] = f2bf(a.x); o[1] = f2bf(a.y); o[2] = f2bf(a.z); o[3] = f2bf(a.w);
  o[4] = f2bf(b.x); o[5] = f2bf(b.y); o[6] = f2bf(b.z); o[7] = f2bf(b.w);
  *((u16x8*)out + i) = o;
}

// ---------------- Wq/Wk/Wv fp32 [512][64] -> bf16 [64][512], 3 weights in one launch ----------------
__global__ __launch_bounds__(256) void k_transpose_w3(const float* __restrict__ w0,
                                                      const float* __restrict__ w1,
                                                      const float* __restrict__ w2,
                                                      unsigned short* __restrict__ out) {
  __shared__ unsigned short tile[64][72];
  int z = blockIdx.z;
  int wsel = z >> 3, hsel = z & 7;
  const float* inb = (wsel == 0 ? w0 : (wsel == 1 ? w1 : w2)) + (size_t)hsel * 512 * 64;
  unsigned short* outb = out + (size_t)z * 512 * 64;
  int r0 = blockIdx.y * 64;
  int tid = threadIdx.x;
  int r = tid >> 2, cq = (tid & 3) * 16;
  const float* src = inb + (size_t)(r0 + r) * 64 + cq;
#pragma unroll
  for (int i = 0; i < 16; i += 4) {
    float4 v = *(const float4*)(src + i);
    tile[r][cq + i + 0] = f2bf(v.x);
    tile[r][cq + i + 1] = f2bf(v.y);
    tile[r][cq + i + 2] = f2bf(v.z);
    tile[r][cq + i + 3] = f2bf(v.w);
  }
  __syncthreads();
  int cr = tid >> 2, rq = (tid & 3) * 16;
  u16x8 o0, o1;
#pragma unroll
  for (int i = 0; i < 8; ++i) o0[i] = tile[rq + i][cr];
#pragma unroll
  for (int i = 0; i < 8; ++i) o1[i] = tile[rq + 8 + i][cr];
  unsigned short* dst = outb + (size_t)cr * 512 + r0 + rq;
  *(u16x8*)dst = o0;
  *(u16x8*)(dst + 8) = o1;
}

// ---------------- Wo fp32 [512][512] -> bf16 [512][512]^T ----------------
__global__ __launch_bounds__(256) void k_transpose_w(const float* __restrict__ in,
                                                     unsigned short* __restrict__ out,
                                                     int rows, int cols) {
  __shared__ unsigned short tile[64][72];
  int c0 = blockIdx.x * 64, r0 = blockIdx.y * 64;
  int tid = threadIdx.x;
  int r = tid >> 2, cq = (tid & 3) * 16;
  const float* src = in + (size_t)(r0 + r) * cols + c0 + cq;
#pragma unroll
  for (int i = 0; i < 16; i += 4) {
    float4 v = *(const float4*)(src + i);
    tile[r][cq + i + 0] = f2bf(v.x);
    tile[r][cq + i + 1] = f2bf(v.y);
    tile[r][cq + i + 2] = f2bf(v.z);
    tile[r][cq + i + 3] = f2bf(v.w);
  }
  __syncthreads();
  int cr = tid >> 2, rq = (tid & 3) * 16;
  u16x8 o0, o1;
#pragma unroll
  for (int i = 0; i < 8; ++i) o0[i] = tile[rq + i][cr];
#pragma unroll
  for (int i = 0; i < 8; ++i) o1[i] = tile[rq + 8 + i][cr];
  unsigned short* dst = out + (size_t)(c0 + cr) * rows + r0 + rq;
  *(u16x8*)dst = o0;
  *(u16x8*)(dst + 8) = o1;
}

// ---------------- 256x256x(K=512) GEMM, 4-phase, minimal sync (R9/R10 structure) ----------------
// KIND 0: x*Wqk^T -> Q,K [B,H,T,HD]; Q pre-scaled by 0.125*log2e for exp2 softmax. grid 512.
// KIND 1: a*Wo^T + bo -> fp32 out. grid 256.
// KIND 2: x*Wv^T -> V^T [B,H,HD,T]. grid 256.
template <int KIND>
__global__ __launch_bounds__(512, 1) void k_gemmP(
    const unsigned short* __restrict__ A,
    const unsigned short* __restrict__ Bmat,
    unsigned short* __restrict__ O0,
    unsigned short* __restrict__ O1,
    const float* __restrict__ bo,
    float* __restrict__ outf) {
  __shared__ unsigned short smem[65536];   // 2 bufs x (A[256][64] | B[256][64])
  const int P = (KIND == 0) ? 64 : 32;     // blocks per XCD
  int xcd = blockIdx.x & 7, g = blockIdx.x >> 3;
  int w = xcd * P + g;
  int mt, nt;
  if (KIND == 0) { mt = w >> 2; nt = w & 3; }
  else           { mt = w >> 1; nt = w & 1; }
  int m0 = mt * 256, n0 = nt * 256;
  int tid = threadIdx.x;
  int wid = tid >> 6, lane = tid & 63;
  int lr = lane & 15, lg = lane >> 4;
  int wm = wid >> 2, wn = wid & 3;

  int srow_off = wid * 16 + (lane >> 3);
  int schunk = (lane & 7) ^ (lane >> 3);   // inverse-swizzled source chunk (rule 21)
  auto stageA = [&](int kb, int buf, int half) {
#pragma unroll
    for (int j = 0; j < 2; ++j) {
      int row = half * 128 + srow_off + j * 8;
      async16(A + (size_t)(m0 + row) * 512 + kb * 64 + schunk * 8,
              smem + buf * 32768 + half * 8192 + (wid * 2 + j) * 512);
    }
  };
  auto stageB = [&](int kb, int buf, int half) {
#pragma unroll
    for (int j = 0; j < 2; ++j) {
      int row = half * 128 + srow_off + j * 8;
      async16(Bmat + (size_t)(n0 + row) * 512 + kb * 64 + schunk * 8,
              smem + buf * 32768 + 16384 + half * 8192 + (wid * 2 + j) * 512);
    }
  };
  auto lda = [&](int buf, int mi, int k32) -> bf16x8 {
    int row = mi * 32 + wm * 16 + lr;
    int ch = (k32 * 4 + lg) ^ (lr & 7);
    return *(const bf16x8*)&smem[buf * 32768 + row * 64 + ch * 8];
  };
  auto ldb = [&](int buf, int ni, int k32) -> bf16x8 {
    int row = ni * 64 + wn * 16 + lr;
    int ch = (k32 * 4 + lg) ^ (lr & 7);
    return *(const bf16x8*)&smem[buf * 32768 + 16384 + row * 64 + ch * 8];
  };

  f32x4 acc[8][4];
#pragma unroll
  for (int mi = 0; mi < 8; ++mi)
#pragma unroll
    for (int ni = 0; ni < 4; ++ni) acc[mi][ni] = (f32x4){0.f, 0.f, 0.f, 0.f};

#define MF(dst, afrag, bfrag)                                                        \
  if constexpr (KIND == 2)                                                           \
    dst = __builtin_amdgcn_mfma_f32_16x16x32_bf16(afrag, bfrag, dst, 0, 0, 0);       \
  else                                                                               \
    dst = __builtin_amdgcn_mfma_f32_16x16x32_bf16(bfrag, afrag, dst, 0, 0, 0);

  // prologue: tile0 halves [A0,B0,A1,B1]; wait A0,B0 (leave A1,B1 in flight)
  stageA(0, 0, 0); stageB(0, 0, 0); stageA(0, 0, 1); stageB(0, 0, 1);
  asm volatile("s_waitcnt vmcnt(4)" ::: "memory");
  __builtin_amdgcn_s_barrier();
  asm volatile("" ::: "memory");

  bf16x8 a03[4][2], a47[4][2], b01[2][2], b23[2][2];
#pragma unroll
  for (int t = 0; t < 8; ++t) {
    int buf = t & 1, nbuf = buf ^ 1;
    const bool st = (t < 7);
    // ---- phase 1: read a03(A0)+b01(B0); stage A0(t+1); MFMA Q00 ----
#pragma unroll
    for (int mi = 0; mi < 4; ++mi) { a03[mi][0] = lda(buf, mi, 0); a03[mi][1] = lda(buf, mi, 1); }
#pragma unroll
    for (int ni = 0; ni < 2; ++ni) { b01[ni][0] = ldb(buf, ni, 0); b01[ni][1] = ldb(buf, ni, 1); }
    if (st) stageA(t + 1, nbuf, 0);
    asm volatile("" ::: "memory");
    __builtin_amdgcn_s_setprio(1);
#pragma unroll
    for (int mi = 0; mi < 4; ++mi)
#pragma unroll
      for (int ni = 0; ni < 2; ++ni)
#pragma unroll
        for (int k = 0; k < 2; ++k) { MF(acc[mi][ni], a03[mi][k], b01[ni][k]); }
    __builtin_amdgcn_s_setprio(0);
    if (st) asm volatile("s_waitcnt vmcnt(4)" ::: "memory");
    else    asm volatile("s_waitcnt vmcnt(2)" ::: "memory");
    __builtin_amdgcn_s_barrier();
    asm volatile("" ::: "memory");
    // ---- phase 2: read a47(A1); stage B0(t+1); MFMA Q10 ----
#pragma unroll
    for (int mi = 0; mi < 4; ++mi) { a47[mi][0] = lda(buf, mi + 4, 0); a47[mi][1] = lda(buf, mi + 4, 1); }
    if (st) stageB(t + 1, nbuf, 0);
    asm volatile("" ::: "memory");
    __builtin_amdgcn_s_setprio(1);
#pragma unroll
    for (int mi = 0; mi < 4; ++mi)
#pragma unroll
      for (int ni = 0; ni < 2; ++ni)
#pragma unroll
        for (int k = 0; k < 2; ++k) { MF(acc[mi + 4][ni], a47[mi][k], b01[ni][k]); }
    __builtin_amdgcn_s_setprio(0);
    if (st) asm volatile("s_waitcnt vmcnt(4)" ::: "memory");
    else    asm volatile("s_waitcnt vmcnt(0)" ::: "memory");
    __builtin_amdgcn_s_barrier();
    asm volatile("" ::: "memory");
    // ---- phase 3: read b23(B1); stage A1(t+1); MFMA Q11; NO vmcnt ----
#pragma unroll
    for (int ni = 0; ni < 2; ++ni) { b23[ni][0] = ldb(buf, ni + 2, 0); b23[ni][1] = ldb(buf, ni + 2, 1); }
    if (st) stageA(t + 1, nbuf, 1);
    asm volatile("" ::: "memory");
    __builtin_amdgcn_s_setprio(1);
#pragma unroll
    for (int mi = 0; mi < 4; ++mi)
#pragma unroll
      for (int ni = 0; ni < 2; ++ni)
#pragma unroll
        for (int k = 0; k < 2; ++k) { MF(acc[mi + 4][ni + 2], a47[mi][k], b23[ni][k]); }
    __builtin_amdgcn_s_setprio(0);
    __builtin_amdgcn_s_barrier();
    asm volatile("" ::: "memory");
    // ---- phase 4: stage B1(t+1); MFMA Q01; vmcnt(4) ----
    if (st) stageB(t + 1, nbuf, 1);
    asm volatile("" ::: "memory");
    __builtin_amdgcn_s_setprio(1);
#pragma unroll
    for (int mi = 0; mi < 4; ++mi)
#pragma unroll
      for (int ni = 0; ni < 2; ++ni)
#pragma unroll
        for (int k = 0; k < 2; ++k) { MF(acc[mi][ni + 2], a03[mi][k], b23[ni][k]); }
    __builtin_amdgcn_s_setprio(0);
    if (st) asm volatile("s_waitcnt vmcnt(4)" ::: "memory");
    __builtin_amdgcn_s_barrier();
    asm volatile("" ::: "memory");
  }
#undef MF

  // ---- epilogues ----
  if constexpr (KIND == 0) {
    int z = n0 >> 9;
    if (z == 0) {
      // fold softmax scale + log2(e) into Q: exp(S/8) == exp2(S * 0.125*log2e)
#pragma unroll
      for (int mi = 0; mi < 8; ++mi)
#pragma unroll
        for (int ni = 0; ni < 4; ++ni) acc[mi][ni] *= 0.18033688011112042f;
    }
    int hbase = (n0 & 511) >> 6;
    int hd0 = wn * 16 + lg * 4;
#pragma unroll
    for (int ni = 0; ni < 4; ++ni) {
      unsigned short* outp = (z ? O1 : O0) + (size_t)(mt * 8 + hbase + ni) * 16384;
#pragma unroll
      for (int mi = 0; mi < 8; ++mi) {
        int tq = mi * 32 + wm * 16 + lr;
        *(bf16x4*)&outp[(size_t)tq * 64 + hd0] = cvt4(acc[mi][ni]);
      }
    }
  } else if constexpr (KIND == 1) {
#pragma unroll
    for (int ni = 0; ni < 4; ++ni) {
      int nb = n0 + ni * 64 + wn * 16 + lg * 4;
      float4 b4 = *(const float4*)&bo[nb];
#pragma unroll
      for (int mi = 0; mi < 8; ++mi) {
        int mg = m0 + mi * 32 + wm * 16 + lr;
        float4 o;
        o.x = acc[mi][ni][0] + b4.x; o.y = acc[mi][ni][1] + b4.y;
        o.z = acc[mi][ni][2] + b4.z; o.w = acc[mi][ni][3] + b4.w;
        *(float4*)&outf[(size_t)mg * 512 + nb] = o;
      }
    }
  } else {
    int hbase = n0 >> 6;
    int hd = wn * 16 + lr;
#pragma unroll
    for (int ni = 0; ni < 4; ++ni) {
      unsigned short* outp = O0 + (size_t)(mt * 8 + hbase + ni) * 16384;
#pragma unroll
      for (int mi = 0; mi < 8; ++mi) {
        int tq = mi * 32 + wm * 16 + lg * 4;
        *(bf16x4*)&outp[(size_t)hd * 256 + tq] = cvt4(acc[mi][ni]);
      }
    }
  }
}

// ---------------- fused causal attention v6: P stays in registers (K=16 PV) ----------------
// pk[nt] (lane: P[t=lr][s=nt*16+lg*4+r]) IS the mfma_16x16x16 B-fragment -> PV needs no
// P LDS / shuffles at all (kills R9's per-k32 LDS round-trip chain). K/V in padded,
// 16B-aligned, immediate-offset LDS: Ksh stride 72 shorts (144B), Vsh stride 260 (520B)
// -> every loop ds_read folds to base+offset:N, bank-spread by construction.
__global__ __launch_bounds__(512, 4) void k_attn2(
    const unsigned short* __restrict__ Qb,
    const unsigned short* __restrict__ Kb,
    const unsigned short* __restrict__ Vtb,
    unsigned short* __restrict__ Ob) {  // [B,T,512] bf16 (concat heads)
  __shared__ unsigned short Ksh[256 * 72];   // 36864 B
  __shared__ unsigned short Vsh[64 * 260];   // 33280 B  (total 70144 -> 2 blocks/CU)
  int bh = blockIdx.x;
  int tid = threadIdx.x, wid = tid >> 6, lane = tid & 63, lr = lane & 15, lg = lane >> 4;
  int bb = bh >> 3, h = bh & 7;
  const unsigned short* Kg = Kb + (size_t)bh * 16384;
  const unsigned short* Vg = Vtb + (size_t)bh * 16384;
  // ---- reg-stage K [256][64] and V^T [64][256] (coalesced 16B, 16B-aligned LDS rows) ----
  int4 gk[4], gv[4];
#pragma unroll
  for (int j = 0; j < 4; ++j) {
    int c = tid + j * 512;
    gk[j] = *(const int4*)(Kg + c * 8);
    gv[j] = *(const int4*)(Vg + c * 8);
  }
  // Q prefetch for both chunks (overlaps the global loads above)
  int ci0 = wid, ci1 = 15 - wid;
  const unsigned short* q0 = Qb + (size_t)bh * 16384 + (size_t)(ci0 * 16 + lr) * 64 + lg * 8;
  const unsigned short* q1 = Qb + (size_t)bh * 16384 + (size_t)(ci1 * 16 + lr) * 64 + lg * 8;
  bf16x8 bq0a = *(const bf16x8*)q0;
  bf16x8 bq0b = *(const bf16x8*)(q0 + 32);
  bf16x8 bq1a = *(const bf16x8*)q1;
  bf16x8 bq1b = *(const bf16x8*)(q1 + 32);
#pragma unroll
  for (int j = 0; j < 4; ++j) {
    int c = tid + j * 512;
    *(int4*)&Ksh[(c >> 3) * 72 + (c & 7) * 8] = gk[j];
    *(int4*)&Vsh[(c >> 5) * 260 + (c & 31) * 8] = gv[j];
  }
  __syncthreads();

  auto do_chunk = [&](int ci, bf16x8 bqa, bf16x8 bqb) {
    int t0 = ci * 16, trow = t0 + lr;
    int ntV = ci + 1;
    f32x4 acc[16];
#pragma unroll
    for (int nt = 0; nt < 16; ++nt)
      if (nt < ntV) {
        acc[nt] = (f32x4){0.f, 0.f, 0.f, 0.f};
        bf16x8 ak0 = *(const bf16x8*)&Ksh[(nt * 16 + lr) * 72 + lg * 8];
        acc[nt] = __builtin_amdgcn_mfma_f32_16x16x32_bf16(ak0, bqa, acc[nt], 0, 0, 0);
        bf16x8 ak1 = *(const bf16x8*)&Ksh[(nt * 16 + lr) * 72 + 32 + lg * 8];
        acc[nt] = __builtin_amdgcn_mfma_f32_16x16x32_bf16(ak1, bqb, acc[nt], 0, 0, 0);
      }
    // acc[nt][r] = S'[t=trow][s=nt*16+lg*4+r], pre-scaled for exp2
    float m0c = -3.0e38f, m1c = -3.0e38f;
#pragma unroll
    for (int nt = 0; nt < 16; ++nt)
      if (nt < ntV) {
        if (nt == ci) {           // diagonal tile: the only masked one
#pragma unroll
          for (int r = 0; r < 4; ++r) {
            float v = acc[nt][r];
            if (lg * 4 + r > lr) v = -1.0e30f;
            acc[nt][r] = v;
          }
        }
        m0c = fmaxf(m0c, fmaxf(acc[nt][0], acc[nt][1]));
        m1c = fmaxf(m1c, fmaxf(acc[nt][2], acc[nt][3]));
      }
    float m = fmaxf(m0c, m1c);
    m = fmaxf(m, __shfl_xor(m, 16));
    m = fmaxf(m, __shfl_xor(m, 32));
    float s4[4] = {0.f, 0.f, 0.f, 0.f};
    bf16x4 pk[16];
#pragma unroll
    for (int nt = 0; nt < 16; ++nt)
      if (nt < ntV) {
#pragma unroll
        for (int r = 0; r < 4; ++r) {
          float p = exp2f(acc[nt][r] - m);
          s4[r] += p;
          pk[nt][r] = (__bf16)p;
        }
      }
    float s = (s4[0] + s4[1]) + (s4[2] + s4[3]);
    s += __shfl_xor(s, 16);
    s += __shfl_xor(s, 32);
    float inv = 1.0f / s;
    // ---- PV: pk is already the 16x16x16 B-fragment; V frags are 8B immediate reads ----
    f32x4 aco[4];
#pragma unroll
    for (int vt = 0; vt < 4; ++vt) aco[vt] = (f32x4){0.f, 0.f, 0.f, 0.f};
#pragma unroll
    for (int nt = 0; nt < 16; ++nt)
      if (nt < ntV) {
#pragma unroll
        for (int vt = 0; vt < 4; ++vt) {
          bf16x4 av = *(const bf16x4*)&Vsh[(vt * 16 + lr) * 260 + nt * 16 + lg * 4];
          aco[vt] = mfma16(av, pk[nt], aco[vt]);
        }
      }
    // aco[vt][r] = O[t=trow][hd=vt*16+lg*4+r]
    unsigned short* obase = Ob + (size_t)(bb * 256 + trow) * 512 + h * 64 + lg * 4;
#pragma unroll
    for (int vt = 0; vt < 4; ++vt) {
      bf16x4 ov;
#pragma unroll
      for (int r = 0; r < 4; ++r) ov[r] = (__bf16)(aco[vt][r] * inv);
      *(bf16x4*)(obase + vt * 16) = ov;
    }
  };

  do_chunk(ci0, bq0a, bq0b);
  do_chunk(ci1, bq1a, bq1b);
}

extern "C" void kernel_launch(void* const* d_in, const int* in_sizes, int n_in,
                              void* d_out, int out_size, void* d_ws, size_t ws_size,
                              hipStream_t stream) {
  (void)in_sizes; (void)n_in; (void)out_size; (void)ws_size;
  const float* x = (const float*)d_in[0];
  const float* Wq = (const float*)d_in[1];
  const float* Wk = (const float*)d_in[2];
  const float* Wv = (const float*)d_in[3];
  const float* Wo = (const float*)d_in[4];
  const float* bo = (const float*)d_in[5];
  float* out = (float*)d_out;
  char* ws = (char*)d_ws;
  const size_t MB = 1024 * 1024;
  unsigned short* Qb = (unsigned short*)(ws);             // 32 MB
  unsigned short* Kb = (unsigned short*)(ws + 32 * MB);   // 32 MB
  unsigned short* Vtb = (unsigned short*)(ws + 64 * MB);  // 32 MB
  unsigned short* xb = (unsigned short*)(ws + 96 * MB);   // 32 MB (reused as attn out)
  unsigned short* Wqt = (unsigned short*)(ws + 128 * MB); // [512][512]; Wkt follows -> [1024][512]
  unsigned short* Wkt = Wqt + 262144;
  unsigned short* Wvt = Wkt + 262144;
  unsigned short* Wot = Wvt + 262144;

  hipLaunchKernelGGL(k_convert_x, dim3(8192), dim3(256), 0, stream, x, xb);
  hipLaunchKernelGGL(k_transpose_w3, dim3(1, 8, 24), dim3(256), 0, stream, Wq, Wk, Wv, Wqt);
  hipLaunchKernelGGL(k_transpose_w, dim3(8, 8, 1), dim3(256), 0, stream, Wo, Wot, 512, 512);
  // QK projection: B = [Wqt;Wkt] = [1024][512]
  hipLaunchKernelGGL((k_gemmP<0>), dim3(512), dim3(512), 0, stream,
                     xb, Wqt, Qb, Kb, (const float*)nullptr, (float*)nullptr);
  // V projection -> V^T
  hipLaunchKernelGGL((k_gemmP<2>), dim3(256), dim3(512), 0, stream,
                     xb, Wvt, Vtb, (unsigned short*)nullptr, (const float*)nullptr, (float*)nullptr);
  hipLaunchKernelGGL(k_attn2, dim3(1024), dim3(512), 0, stream, Qb, Kb, Vtb, xb);
  hipLaunchKernelGGL((k_gemmP<1>), dim3(256), dim3(512), 0, stream,
                     xb, Wot, (unsigned short*)nullptr, (unsigned short*)nullptr, bo, out);
}